// Round 3
// baseline (291.454 us; speedup 1.0000x reference)
//
#include <hip/hip_runtime.h>
#include <math.h>

#define N_NODES 65536
#define G_SEG   512
#define T_ELEMS (300 * 2048)     // T2[zm][j][m]: 300 x 64 x 32 floats = 2.4 MB
#define NH      2048             // h-table intervals over L in [0,10]
#define H_ELEMS ((NH + 1) * 32)  // 2049 x 32 floats = 262 KB

// ---------------------------------------------------------------------------
// Kernel A: T2[zm][j][m] = (1/sqrt(2048)) * sum_u feat_zm[u] * W2[m][l*1024+u*16+wi]
// ---------------------------------------------------------------------------
__global__ __launch_bounds__(256) void build_T(
    const float* __restrict__ emb_z, const float* __restrict__ emb_mol,
    const float* __restrict__ W2, float* __restrict__ T2)
{
    __shared__ float feat[64];
    const int zm = blockIdx.x;
    const int l  = blockIdx.y;
    const int z  = zm / 3, mo = zm % 3;
    const int t  = threadIdx.x;
    if (t < 48)      feat[t] = emb_z[z * 48 + t];
    else if (t < 64) feat[t] = emb_mol[mo * 16 + (t - 48)];
    __syncthreads();

    const float scale = 0.02209708691207961f;  // 1/sqrt(2048)
    const int wi  = t & 15;
    const int mlo = t >> 4;
#pragma unroll
    for (int i = 0; i < 2; ++i) {
        const int m = mlo + 16 * i;
        const float* w2p = W2 + m * 4096 + l * 1024 + wi;
        float acc = 0.f;
#pragma unroll 8
        for (int u = 0; u < 64; ++u)
            acc = fmaf(feat[u], w2p[u * 16], acc);
        T2[zm * 2048 + (l * 16 + wi) * 32 + m] = acc * scale;
    }
}

// ---------------------------------------------------------------------------
// Kernel A2: h-table. Htab[e][m] = SILU_C * silu( sum_k basis_k(L_e) * W1[k][m] )
// ---------------------------------------------------------------------------
__global__ __launch_bounds__(256) void build_H(
    const float* __restrict__ W1, float* __restrict__ Htab, double silu_c)
{
    const int tid = blockIdx.x * blockDim.x + threadIdx.x;
    if (tid >= H_ELEMS) return;
    const int e = tid >> 5, m = tid & 31;
    const double L = (double)e * (10.0 / 2048.0);
    const double c = 1.14136 * exp(2.0);
    double p = 0.0;
    for (int k = 0; k < 10; ++k) {
        const double a = 1.1 * L - (double)k;
        const double b = (double)(k + 2) - 1.1 * L;
        const double basis = (a > 0.0 && b > 0.0) ? c * exp(-2.0 / (a * b)) : 0.0;
        p += basis * (double)W1[k * 32 + m];
    }
    const double h = silu_c * p / (1.0 + exp(-p));
    Htab[e * 32 + m] = (float)h;
}

// ---------------------------------------------------------------------------
// Kernel A3: segment boundaries. seg[g] = lower_bound(batch, g), seg[512] = N.
// ---------------------------------------------------------------------------
__global__ __launch_bounds__(256) void seg_bounds(const int* __restrict__ batch,
                                                  int* __restrict__ seg)
{
    const int g = blockIdx.x * blockDim.x + threadIdx.x;
    if (g > G_SEG) return;
    int lo = 0, hi = N_NODES;
    while (lo < hi) {
        const int mid = (lo + hi) >> 1;
        if (batch[mid] < g) lo = mid + 1; else hi = mid;
    }
    seg[g] = lo;
}

// ---------------------------------------------------------------------------
// Kernel B: one block (1024 thr = 16 waves) per segment. Branch-free node loop,
// register accumulation, LDS block reduction, direct mean write. No atomics.
// Lane j = l*16+wi owns output slots [off + wi*(2l+1) .. +2l].
// ---------------------------------------------------------------------------
__global__ __launch_bounds__(1024, 8) void seg_kernel(
    const float* __restrict__ pos, const int* __restrict__ xz,
    const int* __restrict__ mol, const int* __restrict__ seg,
    const float* __restrict__ Htab, const float* __restrict__ T2,
    float* __restrict__ out)
{
    __shared__ float red[16 * 257];   // [wave][256 outputs], +1 pad vs bank conflicts

    const int g  = blockIdx.x;
    const int s0 = seg[g], s1 = seg[g + 1];
    const int w    = threadIdx.x >> 6;   // 0..15
    const int lane = threadIdx.x & 63;

    const int l  = lane >> 4;
    const int wi = lane & 15;
    const int nl = 2 * l + 1;
    const int off = (l == 0 ? 0 : (l == 1 ? 16 : (l == 2 ? 64 : 144)));
    const int base = off + wi * nl;
    const int m = lane & 31;

    float acc[7];
#pragma unroll
    for (int k = 0; k < 7; ++k) acc[k] = 0.f;

    for (int i = s0 + w; i < s1; i += 16) {
        const float px = pos[3 * i], py = pos[3 * i + 1], pz = pos[3 * i + 2];
        const int zmi = xz[i] * 3 + mol[i];

        const float Lsq = px * px + py * py + pz * pz;
        const float rinv = __builtin_amdgcn_rsqf(Lsq);
        const float L = Lsq * rinv;

        // radial MLP via table lerp
        float t = L * 204.8f;
        int i0 = (int)t;
        i0 = min(i0, NH - 1);
        const float fr = fminf(t - (float)i0, 1.f);
        const float h0 = Htab[i0 * 32 + m];
        const float h1 = Htab[i0 * 32 + 32 + m];
        const float hm = fmaf(fr, h1 - h0, h0);

        // xw[j] = sum_m h[m] * T2[zm][j][m]  -- 4 independent partial chains
        const float4* Tp = reinterpret_cast<const float4*>(T2 + (size_t)zmi * 2048 + lane * 32);
        float xw0 = 0.f, xw1 = 0.f, xw2 = 0.f, xw3 = 0.f;
#pragma unroll
        for (int q = 0; q < 8; q += 4) {
            const float4 t0 = Tp[q + 0];
            const float4 t1 = Tp[q + 1];
            const float4 t2 = Tp[q + 2];
            const float4 t3 = Tp[q + 3];
            xw0 = fmaf(__shfl(hm, 4 * q + 0),  t0.x, xw0);
            xw1 = fmaf(__shfl(hm, 4 * q + 1),  t0.y, xw1);
            xw2 = fmaf(__shfl(hm, 4 * q + 2),  t0.z, xw2);
            xw3 = fmaf(__shfl(hm, 4 * q + 3),  t0.w, xw3);
            xw0 = fmaf(__shfl(hm, 4 * q + 4),  t1.x, xw0);
            xw1 = fmaf(__shfl(hm, 4 * q + 5),  t1.y, xw1);
            xw2 = fmaf(__shfl(hm, 4 * q + 6),  t1.z, xw2);
            xw3 = fmaf(__shfl(hm, 4 * q + 7),  t1.w, xw3);
            xw0 = fmaf(__shfl(hm, 4 * q + 8),  t2.x, xw0);
            xw1 = fmaf(__shfl(hm, 4 * q + 9),  t2.y, xw1);
            xw2 = fmaf(__shfl(hm, 4 * q + 10), t2.z, xw2);
            xw3 = fmaf(__shfl(hm, 4 * q + 11), t2.w, xw3);
            xw0 = fmaf(__shfl(hm, 4 * q + 12), t3.x, xw0);
            xw1 = fmaf(__shfl(hm, 4 * q + 13), t3.y, xw1);
            xw2 = fmaf(__shfl(hm, 4 * q + 14), t3.z, xw2);
            xw3 = fmaf(__shfl(hm, 4 * q + 15), t3.w, xw3);
        }
        const float xwv = (xw0 + xw1) + (xw2 + xw3);

        // spherical harmonics (component normalization)
        const float ux = px * rinv, uy = py * rinv, uz = pz * rinv;
        const float s3 = 1.7320508075688772f, s5 = 2.2360679774997896f, s7 = 2.6457513110645907f;
        const float y2 = uy * uy, x2z2 = ux * ux + uz * uz;
        const float s20 = s3 * ux * uz;
        const float s21 = s3 * ux * uy;
        const float s22 = y2 - 0.5f * x2z2;
        const float s23 = s3 * uy * uz;
        const float s24 = 0.5f * s3 * (uz * uz - ux * ux);

        float shv[7];
#pragma unroll
        for (int k = 0; k < 7; ++k) shv[k] = 0.f;
        if (l == 0) {
            shv[0] = 1.f;
        } else if (l == 1) {
            shv[0] = s3 * ux; shv[1] = s3 * uy; shv[2] = s3 * uz;
        } else if (l == 2) {
            shv[0] = s5 * s20; shv[1] = s5 * s21; shv[2] = s5 * s22;
            shv[3] = s5 * s23; shv[4] = s5 * s24;
        } else {
            const float c56 = 0.9128709291752769f;  // sqrt(5/6)
            const float c38 = 0.6123724356957945f;  // sqrt(3/8)
            const float s30 = c56 * (s20 * uz + s24 * ux);
            const float s31 = s5 * s20 * uy;
            const float s32 = c38 * (4.f * y2 - x2z2) * ux;
            const float s33 = 0.5f * uy * (2.f * y2 - 3.f * x2z2);
            const float s34 = c38 * uz * (4.f * y2 - x2z2);
            const float s35 = s5 * s24 * uy;
            const float s36 = c56 * (s24 * uz - s20 * ux);
            shv[0] = s7 * s30; shv[1] = s7 * s31; shv[2] = s7 * s32;
            shv[3] = s7 * s33; shv[4] = s7 * s34; shv[5] = s7 * s35; shv[6] = s7 * s36;
        }

#pragma unroll
        for (int k = 0; k < 7; ++k)
            if (k < nl) acc[k] = fmaf(xwv, shv[k], acc[k]);
    }

    // block reduction: each lane deposits its owned slots
#pragma unroll
    for (int k = 0; k < 7; ++k)
        if (k < nl) red[w * 257 + base + k] = acc[k];
    __syncthreads();

    if (threadIdx.x < 256) {
        float s = 0.f;
#pragma unroll
        for (int ww = 0; ww < 16; ++ww) s += red[ww * 257 + threadIdx.x];
        const float cnt = (float)(s1 - s0);
        out[g * 256 + threadIdx.x] = s / fmaxf(cnt, 1.f);
    }
}

// ---------------------------------------------------------------------------
static double silu_c_host()
{
    const int n = 200001;
    const double h = 24.0 / 200000.0;
    double sum = 0.0, prev = 0.0;
    for (int i = 0; i < n; ++i) {
        const double z = -12.0 + h * (double)i;
        const double pdf = exp(-0.5 * z * z) * 0.3989422804014327;
        const double s = z / (1.0 + exp(-z));
        const double f = s * s * pdf;
        if (i) sum += prev + f;
        prev = f;
    }
    sum *= 0.5 * h;
    return 1.0 / sqrt(sum);
}

extern "C" void kernel_launch(void* const* d_in, const int* in_sizes, int n_in,
                              void* d_out, int out_size, void* d_ws, size_t ws_size,
                              hipStream_t stream)
{
    const float* pos     = (const float*)d_in[0];
    const int*   xz      = (const int*)d_in[1];
    const int*   mol     = (const int*)d_in[2];
    const int*   batch   = (const int*)d_in[3];
    const float* emb_z   = (const float*)d_in[4];
    const float* emb_mol = (const float*)d_in[5];
    const float* W1      = (const float*)d_in[6];
    const float* W2      = (const float*)d_in[7];
    float* out = (float*)d_out;

    float* T2   = (float*)d_ws;                        // 2.4 MB
    float* Htab = (float*)d_ws + T_ELEMS;              // 262 KB
    int*   seg  = (int*)((float*)d_ws + T_ELEMS + H_ELEMS);  // 513 ints

    static const double SILU_C_D = silu_c_host();

    dim3 gA(300, 4);
    build_T<<<gA, 256, 0, stream>>>(emb_z, emb_mol, W2, T2);
    build_H<<<(H_ELEMS + 255) / 256, 256, 0, stream>>>(W1, Htab, SILU_C_D);
    seg_bounds<<<3, 256, 0, stream>>>(batch, seg);

    seg_kernel<<<G_SEG, 1024, 0, stream>>>(pos, xz, mol, seg, Htab, T2, out);
}

// Round 4
// 85.138 us; speedup vs baseline: 3.4233x; 3.4233x over previous
//
#include <hip/hip_runtime.h>
#include <math.h>

#define N_NODES 65536
#define G_SEG   512
#define T_ELEMS (300 * 2048)       // T2[zm][j][m]: 300 x 64 x 32 f32 = 2.4 MB
#define NH      8192               // h-table intervals over L in [0,10], nearest-neighbor
#define H_ELEMS ((NH + 1) * 32)    // 262,176 floats = 1.05 MB

// prep kernel block ranges
#define NB_T 1200                  // 300 zm x 4 l
#define NB_H ((H_ELEMS + 255) / 256)   // 1025
#define NB_S 3                     // 513 bounds
#define NB_PREP (NB_T + NB_H + NB_S)

// ---------------------------------------------------------------------------
// prep: three independent roles selected by blockIdx.x.
//  role T: T2[zm][j][m] = (1/sqrt(2048)) * sum_u feat_zm[u] * W2[m][l*1024+u*16+wi]
//  role H: Htab[e][m] = SILU_C * silu( sum_k basis_k(e*10/NH) * W1[k][m] )   (f64)
//  role S: seg[g] = lower_bound(batch, g)
// ---------------------------------------------------------------------------
__global__ __launch_bounds__(256) void prep(
    const float* __restrict__ emb_z, const float* __restrict__ emb_mol,
    const float* __restrict__ W2, const float* __restrict__ W1,
    const int* __restrict__ batch,
    float* __restrict__ T2, float* __restrict__ Htab, int* __restrict__ seg,
    double silu_c)
{
    const int b = blockIdx.x;
    const int t = threadIdx.x;

    if (b < NB_T) {
        __shared__ float feat[64];
        const int zm = b >> 2;
        const int l  = b & 3;
        const int z  = zm / 3, mo = zm % 3;
        if (t < 48)      feat[t] = emb_z[z * 48 + t];
        else if (t < 64) feat[t] = emb_mol[mo * 16 + (t - 48)];
        __syncthreads();

        const float scale = 0.02209708691207961f;  // 1/sqrt(2048)
        const int wi  = t & 15;
        const int mlo = t >> 4;
#pragma unroll
        for (int i = 0; i < 2; ++i) {
            const int m = mlo + 16 * i;
            const float* w2p = W2 + m * 4096 + l * 1024 + wi;
            float acc = 0.f;
#pragma unroll 8
            for (int u = 0; u < 64; ++u)
                acc = fmaf(feat[u], w2p[u * 16], acc);
            T2[zm * 2048 + (l * 16 + wi) * 32 + m] = acc * scale;
        }
    } else if (b < NB_T + NB_H) {
        const int tid = (b - NB_T) * 256 + t;
        if (tid >= H_ELEMS) return;
        const int e = tid >> 5, m = tid & 31;
        const double L = (double)e * (10.0 / (double)NH);
        const double c = 1.14136 * exp(2.0);
        double p = 0.0;
        for (int k = 0; k < 10; ++k) {
            const double a = 1.1 * L - (double)k;
            const double bb = (double)(k + 2) - 1.1 * L;
            // exp(-1/a)*exp(-1/b) = exp(-2/(ab)) since a+b == 2
            const double basis = (a > 0.0 && bb > 0.0) ? c * exp(-2.0 / (a * bb)) : 0.0;
            p += basis * (double)W1[k * 32 + m];
        }
        Htab[e * 32 + m] = (float)(silu_c * p / (1.0 + exp(-p)));
    } else {
        const int g = (b - NB_T - NB_H) * 256 + t;
        if (g > G_SEG) return;
        int lo = 0, hi = N_NODES;
        while (lo < hi) {
            const int mid = (lo + hi) >> 1;
            if (batch[mid] < g) lo = mid + 1; else hi = mid;
        }
        seg[g] = lo;
    }
}

// ---------------------------------------------------------------------------
// seg_kernel: one block (512 thr = 8 waves) per segment. Wave w handles nodes
// s0+w, s0+w+8, ... All per-node broadcast data (pos, zmi, h-row) is accessed
// through wave-uniform (readfirstlane'd) addresses -> scalar loads; the only
// vector traffic is the lane-varying T2 row. Branch-free inner loop, register
// accumulation, LDS block reduction, direct mean write. No atomics, no shfl.
// Lane j = l*16+wi owns output slots [off + wi*(2l+1) .. +2l].
// ---------------------------------------------------------------------------
__global__ __launch_bounds__(512, 4) void seg_kernel(
    const float* __restrict__ pos, const int* __restrict__ xz,
    const int* __restrict__ mol, const int* __restrict__ seg,
    const float* __restrict__ Htab, const float* __restrict__ T2,
    float* __restrict__ out)
{
    __shared__ float red[8 * 257];

    const int g  = blockIdx.x;
    const int s0 = seg[g], s1 = seg[g + 1];
    const int wv   = __builtin_amdgcn_readfirstlane(threadIdx.x >> 6);  // wave id, scalar
    const int lane = threadIdx.x & 63;

    const int l  = lane >> 4;
    const int wi = lane & 15;
    const int nl = 2 * l + 1;
    const int off = (l == 0 ? 0 : (l == 1 ? 16 : (l == 2 ? 64 : 144)));
    const int base = off + wi * nl;

    float acc[7];
#pragma unroll
    for (int k = 0; k < 7; ++k) acc[k] = 0.f;

#pragma unroll 2
    for (int i = s0 + wv; i < s1; i += 8) {
        // wave-uniform node data (scalar loads)
        const float px = pos[3 * i], py = pos[3 * i + 1], pz = pos[3 * i + 2];
        const int zmi = xz[i] * 3 + mol[i];

        const float Lsq = px * px + py * py + pz * pz;
        const float rinv = __builtin_amdgcn_rsqf(Lsq);
        const float L = Lsq * rinv;

        // nearest-neighbor h row (wave-uniform -> scalar loads feeding v_fma)
        const float tt = fminf(L * (float)(NH / 10.0) + 0.5f, (float)NH);
        const int e = __builtin_amdgcn_readfirstlane((int)tt);
        const float* __restrict__ hrow = Htab + e * 32;

        // xw[j] = sum_m h[m] * T2[zmi][j][m] -- 4 independent chains
        const float4* __restrict__ Tp =
            reinterpret_cast<const float4*>(T2 + (size_t)zmi * 2048 + lane * 32);
        float xw0 = 0.f, xw1 = 0.f, xw2 = 0.f, xw3 = 0.f;
#pragma unroll
        for (int q = 0; q < 8; ++q) {
            const float4 tq = Tp[q];
            xw0 = fmaf(hrow[4 * q + 0], tq.x, xw0);
            xw1 = fmaf(hrow[4 * q + 1], tq.y, xw1);
            xw2 = fmaf(hrow[4 * q + 2], tq.z, xw2);
            xw3 = fmaf(hrow[4 * q + 3], tq.w, xw3);
        }
        const float xwv = (xw0 + xw1) + (xw2 + xw3);

        // spherical harmonics (component normalization)
        const float ux = px * rinv, uy = py * rinv, uz = pz * rinv;
        const float s3 = 1.7320508075688772f, s5 = 2.2360679774997896f, s7 = 2.6457513110645907f;
        const float y2 = uy * uy, x2z2 = ux * ux + uz * uz;
        const float s20 = s3 * ux * uz;
        const float s21 = s3 * ux * uy;
        const float s22 = y2 - 0.5f * x2z2;
        const float s23 = s3 * uy * uz;
        const float s24 = 0.5f * s3 * (uz * uz - ux * ux);

        float shv[7];
#pragma unroll
        for (int k = 0; k < 7; ++k) shv[k] = 0.f;
        if (l == 0) {
            shv[0] = 1.f;
        } else if (l == 1) {
            shv[0] = s3 * ux; shv[1] = s3 * uy; shv[2] = s3 * uz;
        } else if (l == 2) {
            shv[0] = s5 * s20; shv[1] = s5 * s21; shv[2] = s5 * s22;
            shv[3] = s5 * s23; shv[4] = s5 * s24;
        } else {
            const float c56 = 0.9128709291752769f;  // sqrt(5/6)
            const float c38 = 0.6123724356957945f;  // sqrt(3/8)
            const float s30 = c56 * (s20 * uz + s24 * ux);
            const float s31 = s5 * s20 * uy;
            const float s32 = c38 * (4.f * y2 - x2z2) * ux;
            const float s33 = 0.5f * uy * (2.f * y2 - 3.f * x2z2);
            const float s34 = c38 * uz * (4.f * y2 - x2z2);
            const float s35 = s5 * s24 * uy;
            const float s36 = c56 * (s24 * uz - s20 * ux);
            shv[0] = s7 * s30; shv[1] = s7 * s31; shv[2] = s7 * s32;
            shv[3] = s7 * s33; shv[4] = s7 * s34; shv[5] = s7 * s35; shv[6] = s7 * s36;
        }

#pragma unroll
        for (int k = 0; k < 7; ++k)
            if (k < nl) acc[k] = fmaf(xwv, shv[k], acc[k]);
    }

    // block reduction: each lane deposits its owned slots
#pragma unroll
    for (int k = 0; k < 7; ++k)
        if (k < nl) red[wv * 257 + base + k] = acc[k];
    __syncthreads();

    if (threadIdx.x < 256) {
        float s = 0.f;
#pragma unroll
        for (int ww = 0; ww < 8; ++ww) s += red[ww * 257 + threadIdx.x];
        const float cnt = (float)(s1 - s0);
        out[g * 256 + threadIdx.x] = s / fmaxf(cnt, 1.f);
    }
}

// ---------------------------------------------------------------------------
static double silu_c_host()
{
    const int n = 200001;
    const double h = 24.0 / 200000.0;
    double sum = 0.0, prev = 0.0;
    for (int i = 0; i < n; ++i) {
        const double z = -12.0 + h * (double)i;
        const double pdf = exp(-0.5 * z * z) * 0.3989422804014327;
        const double s = z / (1.0 + exp(-z));
        const double f = s * s * pdf;
        if (i) sum += prev + f;
        prev = f;
    }
    sum *= 0.5 * h;
    return 1.0 / sqrt(sum);
}

extern "C" void kernel_launch(void* const* d_in, const int* in_sizes, int n_in,
                              void* d_out, int out_size, void* d_ws, size_t ws_size,
                              hipStream_t stream)
{
    const float* pos     = (const float*)d_in[0];
    const int*   xz      = (const int*)d_in[1];
    const int*   mol     = (const int*)d_in[2];
    const int*   batch   = (const int*)d_in[3];
    const float* emb_z   = (const float*)d_in[4];
    const float* emb_mol = (const float*)d_in[5];
    const float* W1      = (const float*)d_in[6];
    const float* W2      = (const float*)d_in[7];
    float* out = (float*)d_out;

    float* T2   = (float*)d_ws;                              // 2.4 MB
    float* Htab = (float*)d_ws + T_ELEMS;                    // 1.05 MB
    int*   seg  = (int*)((float*)d_ws + T_ELEMS + H_ELEMS);  // 513 ints

    static const double SILU_C_D = silu_c_host();

    prep<<<NB_PREP, 256, 0, stream>>>(emb_z, emb_mol, W2, W1, batch,
                                      T2, Htab, seg, SILU_C_D);
    seg_kernel<<<G_SEG, 512, 0, stream>>>(pos, xz, mol, seg, Htab, T2, out);
}